// Round 11
// baseline (958.255 us; speedup 1.0000x reference)
//
#include <hip/hip_runtime.h>

typedef unsigned short u16;
typedef unsigned int u32;
typedef __attribute__((ext_vector_type(8))) short bf16x8;
typedef __attribute__((ext_vector_type(4))) float f32x4;

#define NPAPER  100000
#define NAUTHOR 100000
#define NFIELD  50000
#define FIN     128
#define OUTF    349

#define E_WR 1000000
#define E_RW 1000000
#define E_CI 2000000
#define E_HT 1000000
#define E_RH 1000000
#define E_TOT 6000000

// col-space (edge) offsets, concat order: wr, ci, rh, rw, ht
#define CO_CI 1000000
#define CO_RH 3000000
#define CO_RW 4000000
#define CO_HT 5000000
// deg/node-space offsets
#define DB_WR 0
#define DB_CI 100000
#define DB_RH 200000
#define DB_RW 300000
#define DB_HT 400000
#define NDEG  450000

// binned CSR build: 1024-node buckets, fixed capacity (pure-ci bucket
// lambda=20480, sigma=143; 22528 = +14 sigma). EPB=8192 -> 733 blocks.
#define BSH   10
#define NBUCK 440
#define BCAP  22528
#define EPB   8192
#define NPARTBLK ((E_TOT + EPB - 1) / EPB)

static __device__ __forceinline__ float bf2f(u16 u) {
  union { unsigned int i; float f; } c; c.i = ((unsigned int)u) << 16; return c.f;
}
static __device__ __forceinline__ u16 f2bf(float f) {
  union { float f; unsigned int i; } c; c.f = f;
  unsigned int r = c.i + 0x7fffu + ((c.i >> 16) & 1u);
  return (u16)(r >> 16);
}
static __device__ __forceinline__ float ub2f(u32 b) {
  union { u32 i; float f; } c; c.i = b; return c.f;
}

// async global->LDS 16B (wave-uniform LDS base + lane*16)
static __device__ __forceinline__ void gl_lds16(const u16* g, u16* l) {
  __builtin_amdgcn_global_load_lds(
      (const __attribute__((address_space(1))) void*)g,
      (__attribute__((address_space(3))) void*)l, 16, 0, 0);
}

// ---------------- CSR build ----------------
static __device__ __forceinline__ void edec(int e,
    const int* __restrict__ wr, const int* __restrict__ rw,
    const int* __restrict__ ci, const int* __restrict__ ht,
    const int* __restrict__ rh,
    const int*& ei, int& el, int& db, int& E) {
  if (e < CO_CI)      { ei = wr; el = e;         db = DB_WR; E = E_WR; }
  else if (e < CO_RH) { ei = ci; el = e - CO_CI; db = DB_CI; E = E_CI; }
  else if (e < CO_RW) { ei = rh; el = e - CO_RH; db = DB_RH; E = E_RH; }
  else if (e < CO_HT) { ei = rw; el = e - CO_RW; db = DB_RW; E = E_RW; }
  else                { ei = ht; el = e - CO_HT; db = DB_HT; E = E_HT; }
}

__global__ void initcur_k(int* __restrict__ bcursor, int* __restrict__ gcur) {
  int i = blockIdx.x * 256 + threadIdx.x;
  if (i < NBUCK) bcursor[i] = i * BCAP;
  if (i == 0) *gcur = 0;
}

// ---------------- weight prep args ----------------
struct PrepArgs {
  const float *wl1_wr, *wr1_wr, *b1_wr;
  const float *wl1_rw, *wr1_rw, *b1_rw;
  const float *wl1_ci, *wr1_ci, *b1_ci;
  const float *wl1_ht, *wr1_ht, *b1_ht;
  const float *wl1_rh, *wr1_rh, *b1_rh;
  const float *wl2_wr, *wr2_wr, *b2_wr;
  const float *wl2_ci, *wr2_ci, *b2_ci;
  const float *wl2_rh, *wr2_rh, *b2_rh;
  u16 *BpT, *BaT, *BfT, *B2T;
  float *biasP, *biasA, *biasF, *bias2;
};

// segments: BpT 32768 | BaT 16384 | BfT 16384 | B2T 98304 | biasP 256 | biasA 128 | biasF 128 | bias2 384
#define PREP_TOT 164736
#define PREP_BLKS ((PREP_TOT + 255) / 256)

static __device__ __forceinline__ void prep_body(const PrepArgs& a, int i) {
  if (i >= PREP_TOT) return;
  if (i < 32768) {                 // BpT [256 n][128 k]: n: [ci | rw | ht | sum(wr1_*)]
    int c = i >> 7, k = i & 127;
    float v;
    if (c < 64)       v = a.wl1_ci[k * 64 + c];
    else if (c < 128) v = a.wl1_rw[k * 64 + (c - 64)];
    else if (c < 192) v = a.wl1_ht[k * 64 + (c - 128)];
    else { int cc = c - 192; v = a.wr1_wr[k*64+cc] + a.wr1_ci[k*64+cc] + a.wr1_rh[k*64+cc]; }
    a.BpT[i] = f2bf(v);
  } else if (i < 49152) {          // BaT [128 n][128 k]: [wl1_wr | wr1_rw]
    int j = i - 32768; int c = j >> 7, k = j & 127;
    a.BaT[j] = f2bf((c < 64) ? a.wl1_wr[k*64 + c] : a.wr1_rw[k*64 + (c - 64)]);
  } else if (i < 65536) {          // BfT [128 n][128 k]: [wl1_rh | wr1_ht]
    int j = i - 49152; int c = j >> 7, k = j & 127;
    a.BfT[j] = f2bf((c < 64) ? a.wl1_rh[k*64 + c] : a.wr1_ht[k*64 + (c - 64)]);
  } else if (i < 163840) {         // B2T [384 n][256 k], n>=349 -> 0
    int j = i - 65536; int c = j >> 8, k = j & 255;
    float v = 0.f;
    if (c < 349) {
      if (k < 64)       v = a.wl2_wr[k * 349 + c];
      else if (k < 128) v = a.wl2_ci[(k - 64) * 349 + c];
      else if (k < 192) v = a.wl2_rh[(k - 128) * 349 + c];
      else { int kk = k - 192; v = a.wr2_wr[kk*349+c] + a.wr2_ci[kk*349+c] + a.wr2_rh[kk*349+c]; }
    }
    a.B2T[j] = f2bf(v);
  } else if (i < 164096) {         // biasP 256
    int c = i - 163840;
    a.biasP[c] = (c < 192) ? 0.f : (a.b1_wr[c-192] + a.b1_ci[c-192] + a.b1_rh[c-192]);
  } else if (i < 164224) {         // biasA 128
    int c = i - 164096;
    a.biasA[c] = (c < 64) ? 0.f : a.b1_rw[c - 64];
  } else if (i < 164352) {         // biasF 128
    int c = i - 164224;
    a.biasF[c] = (c < 64) ? 0.f : a.b1_ht[c - 64];
  } else {                         // bias2 384 (padded with 0)
    int c = i - 164352;
    a.bias2[c] = (c < 349) ? (a.b2_wr[c] + a.b2_ci[c] + a.b2_rh[c]) : 0.f;
  }
}

// fused: blocks [0,NPARTBLK) partition edges; blocks [NPARTBLK, +PREP_BLKS) do weight prep
__global__ __launch_bounds__(256) void part_prep_k(
    const int* __restrict__ wr, const int* __restrict__ rw,
    const int* __restrict__ ci, const int* __restrict__ ht,
    const int* __restrict__ rh, int* __restrict__ bcursor,
    unsigned int* __restrict__ tmp, PrepArgs pa) {
  __shared__ int cnt[NBUCK];
  __shared__ int res[NBUCK];
  int tid = threadIdx.x;
  int blk = blockIdx.x;
  if (blk >= NPARTBLK) {
    prep_body(pa, (blk - NPARTBLK) * 256 + tid);
    return;
  }
  for (int i = tid; i < NBUCK; i += 256) cnt[i] = 0;
  __syncthreads();
  int e0 = blk * EPB;
#pragma unroll 4
  for (int it = 0; it < EPB / 256; ++it) {
    int e = e0 + it * 256 + tid;
    if (e < E_TOT) {
      const int* ei; int el, db, E;
      edec(e, wr, rw, ci, ht, rh, ei, el, db, E);
      int g = db + ei[E + el];
      atomicAdd(&cnt[g >> BSH], 1);
    }
  }
  __syncthreads();
  for (int i = tid; i < NBUCK; i += 256) {
    int c = cnt[i];
    res[i] = c ? atomicAdd(&bcursor[i], c) : 0;
  }
  __syncthreads();
  for (int i = tid; i < NBUCK; i += 256) cnt[i] = 0;
  __syncthreads();
#pragma unroll 4
  for (int it = 0; it < EPB / 256; ++it) {
    int e = e0 + it * 256 + tid;
    if (e < E_TOT) {
      const int* ei; int el, db, E;
      edec(e, wr, rw, ci, ht, rh, ei, el, db, E);
      int g = db + ei[E + el];
      int src = ei[el];
      int b = g >> BSH;
      int p = res[b] + atomicAdd(&cnt[b], 1);
      tmp[p] = ((unsigned int)(g & 1023) << 17) | (unsigned int)src;
    }
  }
}

// ---------------- MFMA GEMM core (bf16, 128x128 tile, BK=32, 4 waves 2x2) ----------------
static __device__ __forceinline__ void stC(float* p, float v) { *p = v; }
static __device__ __forceinline__ void stC(u16* p, float v)   { *p = f2bf(v); }

// f32 -> packed bf16 via v_cvt_pk_bf16_f32 (RTNE, same rounding as f2bf)
static __device__ __forceinline__ void ld8(const float* p, uint4& v) {
  const float4 f0 = *(const float4*)p;
  const float4 f1 = *(const float4*)(p + 4);
  asm("v_cvt_pk_bf16_f32 %0, %1, %2" : "=v"(v.x) : "v"(f0.x), "v"(f0.y));
  asm("v_cvt_pk_bf16_f32 %0, %1, %2" : "=v"(v.y) : "v"(f0.z), "v"(f0.w));
  asm("v_cvt_pk_bf16_f32 %0, %1, %2" : "=v"(v.z) : "v"(f1.x), "v"(f1.y));
  asm("v_cvt_pk_bf16_f32 %0, %1, %2" : "=v"(v.w) : "v"(f1.z), "v"(f1.w));
}

// LDS content: row r, chunk c holds global chunk (c ^ ((r>>1)&3)).
// bf16 A and Bt stage via global_load_lds with pre-swizzled SOURCE chunk + linear dest.
// f32 A stages via regs with cvt_pk f32->bf16.
template <typename AT, typename CT>
static __device__ __forceinline__ void gemm_core(
    const AT* __restrict__ A, const u16* __restrict__ Bt,
    const float* __restrict__ bias, CT* __restrict__ C,
    int M, int N, int K, int row0, int col0, u16* As, u16* Bs) {
  int tid = threadIdx.x;
  int lane = tid & 63;
  int w = tid >> 6;
  int wr = (w >> 1) << 6, wc = (w & 1) << 6;
  int l15 = lane & 15, lh = lane >> 4;
  f32x4 acc[4][4] = {};
  int rchunk = ((lh ^ ((l15 >> 1) & 3)) << 3);
  for (int k0 = 0; k0 < K; k0 += 32) {
    __syncthreads();
#pragma unroll
    for (int it = 0; it < 2; ++it) {             // A: 128 rows x 32 k
      int idx = tid + it * 256;
      int r = idx >> 2, kh = idx & 3;
      int skh = kh ^ ((r >> 1) & 3);
      if constexpr (__is_same(AT, u16)) {
        gl_lds16(A + (size_t)(row0 + r) * K + k0 + skh * 8,
                 As + (size_t)(idx & ~63) * 8);
      } else {
        uint4 v = {0u, 0u, 0u, 0u};
        int row = row0 + r;
        if (row < M) ld8(A + (size_t)row * K + k0 + skh * 8, v);
        *(uint4*)&As[(size_t)idx * 8] = v;
      }
    }
#pragma unroll
    for (int it = 0; it < 2; ++it) {             // B: 128 cols x 32 k (always bf16)
      int idx = tid + it * 256;
      int r = idx >> 2, kh = idx & 3;
      int skh = kh ^ ((r >> 1) & 3);
      gl_lds16(Bt + (size_t)(col0 + r) * K + k0 + skh * 8,
               Bs + (size_t)(idx & ~63) * 8);
    }
    __syncthreads();
    bf16x8 af[4], bfr[4];
#pragma unroll
    for (int m = 0; m < 4; ++m)
      af[m] = *(const bf16x8*)&As[(wr + m * 16 + l15) * 32 + rchunk];
#pragma unroll
    for (int n = 0; n < 4; ++n)
      bfr[n] = *(const bf16x8*)&Bs[(wc + n * 16 + l15) * 32 + rchunk];
#pragma unroll
    for (int m = 0; m < 4; ++m)
#pragma unroll
      for (int n = 0; n < 4; ++n)
        acc[m][n] = __builtin_amdgcn_mfma_f32_16x16x32_bf16(af[m], bfr[n], acc[m][n], 0, 0, 0);
  }
#pragma unroll
  for (int n = 0; n < 4; ++n) {
    int col = col0 + wc + n * 16 + l15;
    if (col >= N) continue;
    float bv = bias[col];
#pragma unroll
    for (int m = 0; m < 4; ++m) {
      int rowb = row0 + wr + m * 16 + (lh << 2);
#pragma unroll
      for (int j = 0; j < 4; ++j) {
        int r = rowb + j;
        if (r < M) stC(C + (size_t)r * N + col, acc[m][n][j] + bv);
      }
    }
  }
}

// fused: blocks [0,2737) = layer-1 GEMMs; blocks [2737, 2737+440) = build_bucket.
// Legal: both depend only on part_prep_k; tmp aliases d_out (not yp), so GEMM's
// yp/ya/yf writes don't race build's tmp reads.
__global__ __launch_bounds__(256) void build_gemm_k(
    const float* __restrict__ xp, const float* __restrict__ xa, const float* __restrict__ xf,
    const u16* __restrict__ BpT, const u16* __restrict__ BaT, const u16* __restrict__ BfT,
    const float* __restrict__ biasP, const float* __restrict__ biasA, const float* __restrict__ biasF,
    u16* __restrict__ yp, u16* __restrict__ ya, u16* __restrict__ yf,
    const unsigned int* __restrict__ tmp, const int* __restrict__ bcursor,
    int* __restrict__ gcur, int* __restrict__ rbeg, int* __restrict__ rend,
    int* __restrict__ colall) {
  __shared__ __align__(16) u16 As[128 * 32];
  __shared__ __align__(16) u16 Bs[128 * 32];
  __shared__ int sdeg[1024];
  __shared__ int ssum[256];
  __shared__ int sbase;
  int tid = threadIdx.x;
  int id = blockIdx.x;
  if (id < 1564) {
    int rx = id % 782, cy = id / 782;
    gemm_core<float, u16>(xp, BpT, biasP, yp, NPAPER, 256, FIN, rx * 128, cy * 128, As, Bs);
    return;
  } else if (id < 2346) {
    gemm_core<float, u16>(xa, BaT, biasA, ya, NAUTHOR, 128, FIN, (id - 1564) * 128, 0, As, Bs);
    return;
  } else if (id < 2737) {
    gemm_core<float, u16>(xf, BfT, biasF, yf, NFIELD, 128, FIN, (id - 2346) * 128, 0, As, Bs);
    return;
  }
  // ---- build_bucket branch ----
  int b = id - 2737;
  int beg = b * BCAP, end = bcursor[b];
  for (int i = tid; i < 1024; i += 256) sdeg[i] = 0;
  __syncthreads();
  for (int i = beg + tid; i < end; i += 256) {
    atomicAdd(&sdeg[(int)(tmp[i] >> 17)], 1);
  }
  __syncthreads();
  int i0 = tid * 4;
  int v0 = sdeg[i0], v1 = sdeg[i0 + 1], v2 = sdeg[i0 + 2], v3 = sdeg[i0 + 3];
  int s = v0 + v1 + v2 + v3;
  ssum[tid] = s; __syncthreads();
  int val = s;
  for (int off = 1; off < 256; off <<= 1) {
    int t = (tid >= off) ? ssum[tid - off] : 0;
    __syncthreads();
    val += t; ssum[tid] = val;
    __syncthreads();
  }
  if (tid == 255) sbase = atomicAdd(gcur, val);   // val@255 = bucket total
  __syncthreads();
  int base = sbase + (val - s);
  int e0 = base, e1 = base + v0, e2 = base + v0 + v1, e3 = base + v0 + v1 + v2;
  int n0 = b << BSH;
  if (n0 + i0     < NDEG) { rbeg[n0 + i0]     = e0; rend[n0 + i0]     = e0 + v0; }
  if (n0 + i0 + 1 < NDEG) { rbeg[n0 + i0 + 1] = e1; rend[n0 + i0 + 1] = e1 + v1; }
  if (n0 + i0 + 2 < NDEG) { rbeg[n0 + i0 + 2] = e2; rend[n0 + i0 + 2] = e2 + v2; }
  if (n0 + i0 + 3 < NDEG) { rbeg[n0 + i0 + 3] = e3; rend[n0 + i0 + 3] = e3 + v3; }
  __syncthreads();
  sdeg[i0] = e0; sdeg[i0 + 1] = e1; sdeg[i0 + 2] = e2; sdeg[i0 + 3] = e3;
  __syncthreads();
  for (int i = beg + tid; i < end; i += 256) {
    unsigned int pk = tmp[i];
    int p = atomicAdd(&sdeg[(int)(pk >> 17)], 1);
    colall[p] = (int)(pk & 0x1FFFFu);
  }
}

// final GEMM: A bf16 (yp), C fp32 (out). Tail rows >= M read <=49KB past yp into ya
// (valid workspace); results discarded by predicated C-write.
__global__ __launch_bounds__(256) void gemm_out_k(
    const u16* __restrict__ A, const u16* __restrict__ Bt,
    const float* __restrict__ bias, float* __restrict__ C) {
  __shared__ __align__(16) u16 As[128 * 32];
  __shared__ __align__(16) u16 Bs[128 * 32];
  gemm_core<u16, float>(A, Bt, bias, C, NPAPER, OUTF, 256,
                        blockIdx.x * 128, blockIdx.y * 128, As, Bs);
}

// ---------------- aggregation: 2 nodes/wave (32 lanes/node), u32 gathers, 8-deep ----------------
// CFG 0: L1 paper (wr+ci+rh means + self + relu -> yp[:,192:256])
// CFG 1: L1 author (rw mean + self + relu -> ya[:,64:128])
// CFG 2: L1 field (ht mean + self + relu -> yf[:,64:128])
// CFG 3: L2 paper (wr/ci/rh means over a1/p1/f1 -> yp[:,0:192])
template <int CFG>
static __device__ __forceinline__ void agg_body(
    int node, int l, const int* __restrict__ rbeg, const int* __restrict__ rend,
    const int* __restrict__ colall,
    u16* __restrict__ ya, u16* __restrict__ yp, u16* __restrict__ yf) {
  constexpr int T = (CFG == 0 || CFG == 3) ? 3 : 1;
  constexpr bool CMB = (CFG != 3);
  constexpr int rpbs[4][3] = {{DB_WR, DB_CI, DB_RH}, {DB_RW, 0, 0}, {DB_HT, 0, 0}, {DB_WR, DB_CI, DB_RH}};
  constexpr int ssel[4][3] = {{0, 1, 2}, {1, 1, 1}, {1, 1, 1}, {0, 1, 2}};
  constexpr int st2s[4][3] = {{64, 128, 64}, {128, 128, 128}, {128, 128, 128}, {64, 128, 64}};
  constexpr int co2s[4][3] = {{0, 0, 0}, {32, 32, 32}, {64, 64, 64}, {32, 96, 32}};
  constexpr int SST2 = (CFG == 0) ? 128 : 64;
  constexpr int SCO2 = (CFG == 0) ? 96 : 32;
  constexpr int OST2 = (CFG == 0 || CFG == 3) ? 128 : 64;
  constexpr int OCO2 = (CFG == 0) ? 96 : ((CFG == 3) ? 0 : 32);

  float totx = 0.f, toty = 0.f;
#pragma unroll
  for (int t = 0; t < T; ++t) {
    const u16* sp = (ssel[CFG][t] == 0) ? ya : ((ssel[CFG][t] == 1) ? yp : yf);
    const u32* s32 = (const u32*)sp + co2s[CFG][t] + l;
    const int st2 = st2s[CFG][t];
    int b = rbeg[rpbs[CFG][t] + node];
    int e = rend[rpbs[CFG][t] + node];
    float ax = 0.f, ay = 0.f;
    for (int i = b; __any(i < e); i += 8) {
      u32 v0 = 0, v1 = 0, v2 = 0, v3 = 0, v4 = 0, v5 = 0, v6 = 0, v7 = 0;
      if (i < e)     v0 = s32[colall[i]     * st2];
      if (i + 1 < e) v1 = s32[colall[i + 1] * st2];
      if (i + 2 < e) v2 = s32[colall[i + 2] * st2];
      if (i + 3 < e) v3 = s32[colall[i + 3] * st2];
      if (i + 4 < e) v4 = s32[colall[i + 4] * st2];
      if (i + 5 < e) v5 = s32[colall[i + 5] * st2];
      if (i + 6 < e) v6 = s32[colall[i + 6] * st2];
      if (i + 7 < e) v7 = s32[colall[i + 7] * st2];
      ax += ((ub2f(v0 << 16) + ub2f(v1 << 16)) + (ub2f(v2 << 16) + ub2f(v3 << 16))) +
            ((ub2f(v4 << 16) + ub2f(v5 << 16)) + (ub2f(v6 << 16) + ub2f(v7 << 16)));
      ay += ((ub2f(v0 & 0xffff0000u) + ub2f(v1 & 0xffff0000u)) +
             (ub2f(v2 & 0xffff0000u) + ub2f(v3 & 0xffff0000u))) +
            ((ub2f(v4 & 0xffff0000u) + ub2f(v5 & 0xffff0000u)) +
             (ub2f(v6 & 0xffff0000u) + ub2f(v7 & 0xffff0000u)));
    }
    float dn = 1.f / fmaxf((float)(e - b), 1.f);
    ax *= dn; ay *= dn;
    if constexpr (CMB) { totx += ax; toty += ay; }
    else {
      u32* o32 = (u32*)yp + (size_t)node * 128 + t * 32 + l;
      *o32 = (u32)f2bf(ax) | ((u32)f2bf(ay) << 16);
    }
  }
  if constexpr (CMB) {
    const u16* sb = (CFG == 0) ? yp : ((CFG == 1) ? ya : yf);
    u32 sv = ((const u32*)sb)[(size_t)node * SST2 + SCO2 + l];
    totx += ub2f(sv << 16);
    toty += ub2f(sv & 0xffff0000u);
    totx = fmaxf(totx, 0.f);
    toty = fmaxf(toty, 0.f);
    u16* ob = (CFG == 0) ? yp : ((CFG == 1) ? ya : yf);
    ((u32*)ob)[(size_t)node * OST2 + OCO2 + l] = (u32)f2bf(totx) | ((u32)f2bf(toty) << 16);
  }
}

// fused L1 aggregation: blocks [0,12500)=paper, [12500,25000)=author, [25000,31250)=field
__global__ __launch_bounds__(256) void agg_l1_k(
    const int* __restrict__ rbeg, const int* __restrict__ rend,
    const int* __restrict__ colall,
    u16* __restrict__ ya, u16* __restrict__ yp, u16* __restrict__ yf) {
  int tid = threadIdx.x;
  int lane = tid & 63;
  int half = lane >> 5, l = lane & 31;
  int blk = blockIdx.x;
  if (blk < 12500) {
    int node = (int)(((blk * 256u + (unsigned)tid) >> 6) * 2 + half);
    agg_body<0>(node, l, rbeg, rend, colall, ya, yp, yf);
  } else if (blk < 25000) {
    int node = (int)((((blk - 12500) * 256u + (unsigned)tid) >> 6) * 2 + half);
    agg_body<1>(node, l, rbeg, rend, colall, ya, yp, yf);
  } else {
    int node = (int)((((blk - 25000) * 256u + (unsigned)tid) >> 6) * 2 + half);
    agg_body<2>(node, l, rbeg, rend, colall, ya, yp, yf);
  }
}

__global__ __launch_bounds__(256) void agg_l2_k(
    const int* __restrict__ rbeg, const int* __restrict__ rend,
    const int* __restrict__ colall,
    u16* __restrict__ ya, u16* __restrict__ yp, u16* __restrict__ yf) {
  int tid = threadIdx.x;
  int lane = tid & 63;
  int half = lane >> 5, l = lane & 31;
  int node = (int)(((blockIdx.x * 256u + (unsigned)tid) >> 6) * 2 + half);
  agg_body<3>(node, l, rbeg, rend, colall, ya, yp, yf);
}

// ---------------- host ----------------
extern "C" void kernel_launch(void* const* d_in, const int* in_sizes, int n_in,
                              void* d_out, int out_size, void* d_ws, size_t ws_size,
                              hipStream_t stream) {
  (void)in_sizes; (void)n_in; (void)out_size; (void)ws_size;
  const float* x_paper  = (const float*)d_in[0];
  const float* x_author = (const float*)d_in[1];
  const float* x_field  = (const float*)d_in[2];
  const int* ei_wr = (const int*)d_in[3];
  const int* ei_rw = (const int*)d_in[4];
  const int* ei_ci = (const int*)d_in[5];
  const int* ei_ht = (const int*)d_in[6];
  const int* ei_rh = (const int*)d_in[7];
  float* out = (float*)d_out;

  char* w = (char*)d_ws;
  auto alloc = [&](size_t b) { char* p = w; w += (b + 255) & ~(size_t)255; return p; };
  int* rbeg     = (int*)alloc((size_t)NDEG * 4);
  int* rend     = (int*)alloc((size_t)NDEG * 4);
  int* colall   = (int*)alloc((size_t)E_TOT * 4);
  int* bcursor  = (int*)alloc(512 * 4);
  int* gcur     = (int*)alloc(256);
  // yp cols: [0:64]=ci-proj [64:128]=rw-proj [128:192]=ht-proj [192:256]=self -> p1; later cols 0:192 = L2 means
  u16* yp = (u16*)alloc((size_t)NPAPER * 256 * 2);
  // ya cols: [0:64]=wr-proj, [64:128]=self -> a1
  u16* ya = (u16*)alloc((size_t)NAUTHOR * 128 * 2);
  // yf cols: [0:64]=rh-proj, [64:128]=self -> f1
  u16* yf = (u16*)alloc((size_t)NFIELD * 128 * 2);
  u16* BpT   = (u16*)alloc(32768 * 2);
  u16* BaT   = (u16*)alloc(16384 * 2);
  u16* BfT   = (u16*)alloc(16384 * 2);
  u16* B2T   = (u16*)alloc(98304 * 2);
  float* biasP = (float*)alloc(256 * 4);
  float* biasA = (float*)alloc(128 * 4);
  float* biasF = (float*)alloc(128 * 4);
  float* bias2 = (float*)alloc(384 * 4);

  // tmp (440*22528*4 = 39.6 MB) aliases d_out (139.6 MB): read only until
  // build completes; gemm_out_k fully overwrites out at the end.
  unsigned int* tmp = (unsigned int*)d_out;

  PrepArgs pa;
  pa.wl1_wr = (const float*)d_in[8];  pa.wr1_wr = (const float*)d_in[9];  pa.b1_wr = (const float*)d_in[10];
  pa.wl1_rw = (const float*)d_in[11]; pa.wr1_rw = (const float*)d_in[12]; pa.b1_rw = (const float*)d_in[13];
  pa.wl1_ci = (const float*)d_in[14]; pa.wr1_ci = (const float*)d_in[15]; pa.b1_ci = (const float*)d_in[16];
  pa.wl1_ht = (const float*)d_in[17]; pa.wr1_ht = (const float*)d_in[18]; pa.b1_ht = (const float*)d_in[19];
  pa.wl1_rh = (const float*)d_in[20]; pa.wr1_rh = (const float*)d_in[21]; pa.b1_rh = (const float*)d_in[22];
  pa.wl2_wr = (const float*)d_in[23]; pa.wr2_wr = (const float*)d_in[24]; pa.b2_wr = (const float*)d_in[25];
  pa.wl2_ci = (const float*)d_in[26]; pa.wr2_ci = (const float*)d_in[27]; pa.b2_ci = (const float*)d_in[28];
  pa.wl2_rh = (const float*)d_in[29]; pa.wr2_rh = (const float*)d_in[30]; pa.b2_rh = (const float*)d_in[31];
  pa.BpT = BpT; pa.BaT = BaT; pa.BfT = BfT; pa.B2T = B2T;
  pa.biasP = biasP; pa.biasA = biasA; pa.biasF = biasF; pa.bias2 = bias2;

  initcur_k<<<2, 256, 0, stream>>>(bcursor, gcur);
  part_prep_k<<<NPARTBLK + PREP_BLKS, 256, 0, stream>>>(
      ei_wr, ei_rw, ei_ci, ei_ht, ei_rh, bcursor, tmp, pa);

  // fused: layer-1 GEMMs (blocks 0..2736) || CSR bucket build (blocks 2737..3176)
  build_gemm_k<<<2737 + NBUCK, 256, 0, stream>>>(
      x_paper, x_author, x_field, BpT, BaT, BfT, biasP, biasA, biasF,
      yp, ya, yf, tmp, bcursor, gcur, rbeg, rend, colall);

  // layer-1 aggregation (fused): p1 -> yp[:,192:256], a1 -> ya[:,64:128], f1 -> yf[:,64:128]
  agg_l1_k<<<31250, 256, 0, stream>>>(rbeg, rend, colall, ya, yp, yf);
  // layer-2 aggregation: means into yp[:,0:192] (reads a1, p1, f1)
  agg_l2_k<<<12500, 256, 0, stream>>>(rbeg, rend, colall, ya, yp, yf);

  // final fused GEMM: [m_wr | m_ci | m_rh | p1] @ B2T + bias2 -> out  (N=349 padded to 384)
  gemm_out_k<<<dim3(782, 3), 256, 0, stream>>>(yp, B2T, bias2, out);
}

// Round 12
// 942.476 us; speedup vs baseline: 1.0167x; 1.0167x over previous
//
#include <hip/hip_runtime.h>

typedef unsigned short u16;
typedef unsigned int u32;
typedef __attribute__((ext_vector_type(8))) short bf16x8;
typedef __attribute__((ext_vector_type(4))) float f32x4;

#define NPAPER  100000
#define NAUTHOR 100000
#define NFIELD  50000
#define FIN     128
#define OUTF    349

#define E_WR 1000000
#define E_RW 1000000
#define E_CI 2000000
#define E_HT 1000000
#define E_RH 1000000
#define E_TOT 6000000

// col-space (edge) offsets, concat order: wr, ci, rh, rw, ht
#define CO_CI 1000000
#define CO_RH 3000000
#define CO_RW 4000000
#define CO_HT 5000000
// deg/node-space offsets
#define DB_WR 0
#define DB_CI 100000
#define DB_RH 200000
#define DB_RW 300000
#define DB_HT 400000
#define NDEG  450000

// binned CSR build: 1024-node buckets, fixed capacity (pure-ci bucket
// lambda=20480, sigma=143; 22528 = +14 sigma). EPB=8192 -> 733 blocks.
#define BSH   10
#define NBUCK 440
#define BCAP  22528
#define EPB   8192
#define NPARTBLK ((E_TOT + EPB - 1) / EPB)

static __device__ __forceinline__ float bf2f(u16 u) {
  union { unsigned int i; float f; } c; c.i = ((unsigned int)u) << 16; return c.f;
}
static __device__ __forceinline__ u16 f2bf(float f) {
  union { float f; unsigned int i; } c; c.f = f;
  unsigned int r = c.i + 0x7fffu + ((c.i >> 16) & 1u);
  return (u16)(r >> 16);
}
static __device__ __forceinline__ float ub2f(u32 b) {
  union { u32 i; float f; } c; c.i = b; return c.f;
}

// async global->LDS 16B (wave-uniform LDS base + lane*16)
static __device__ __forceinline__ void gl_lds16(const u16* g, u16* l) {
  __builtin_amdgcn_global_load_lds(
      (const __attribute__((address_space(1))) void*)g,
      (__attribute__((address_space(3))) void*)l, 16, 0, 0);
}

// ---------------- CSR build ----------------
static __device__ __forceinline__ void edec(int e,
    const int* __restrict__ wr, const int* __restrict__ rw,
    const int* __restrict__ ci, const int* __restrict__ ht,
    const int* __restrict__ rh,
    const int*& ei, int& el, int& db, int& E) {
  if (e < CO_CI)      { ei = wr; el = e;         db = DB_WR; E = E_WR; }
  else if (e < CO_RH) { ei = ci; el = e - CO_CI; db = DB_CI; E = E_CI; }
  else if (e < CO_RW) { ei = rh; el = e - CO_RH; db = DB_RH; E = E_RH; }
  else if (e < CO_HT) { ei = rw; el = e - CO_RW; db = DB_RW; E = E_RW; }
  else                { ei = ht; el = e - CO_HT; db = DB_HT; E = E_HT; }
}

__global__ void initcur_k(int* __restrict__ bcursor, int* __restrict__ gcur) {
  int i = blockIdx.x * 256 + threadIdx.x;
  if (i < NBUCK) bcursor[i] = i * BCAP;
  if (i == 0) *gcur = 0;
}

// ---------------- weight prep args ----------------
struct PrepArgs {
  const float *wl1_wr, *wr1_wr, *b1_wr;
  const float *wl1_rw, *wr1_rw, *b1_rw;
  const float *wl1_ci, *wr1_ci, *b1_ci;
  const float *wl1_ht, *wr1_ht, *b1_ht;
  const float *wl1_rh, *wr1_rh, *b1_rh;
  const float *wl2_wr, *wr2_wr, *b2_wr;
  const float *wl2_ci, *wr2_ci, *b2_ci;
  const float *wl2_rh, *wr2_rh, *b2_rh;
  u16 *BpT, *BaT, *BfT, *B2T;
  float *biasP, *biasA, *biasF, *bias2;
};

// segments: BpT 32768 | BaT 16384 | BfT 16384 | B2T 98304 | biasP 256 | biasA 128 | biasF 128 | bias2 384
#define PREP_TOT 164736
#define PREP_BLKS ((PREP_TOT + 255) / 256)

static __device__ __forceinline__ void prep_body(const PrepArgs& a, int i) {
  if (i >= PREP_TOT) return;
  if (i < 32768) {                 // BpT [256 n][128 k]: n: [ci | rw | ht | sum(wr1_*)]
    int c = i >> 7, k = i & 127;
    float v;
    if (c < 64)       v = a.wl1_ci[k * 64 + c];
    else if (c < 128) v = a.wl1_rw[k * 64 + (c - 64)];
    else if (c < 192) v = a.wl1_ht[k * 64 + (c - 128)];
    else { int cc = c - 192; v = a.wr1_wr[k*64+cc] + a.wr1_ci[k*64+cc] + a.wr1_rh[k*64+cc]; }
    a.BpT[i] = f2bf(v);
  } else if (i < 49152) {          // BaT [128 n][128 k]: [wl1_wr | wr1_rw]
    int j = i - 32768; int c = j >> 7, k = j & 127;
    a.BaT[j] = f2bf((c < 64) ? a.wl1_wr[k*64 + c] : a.wr1_rw[k*64 + (c - 64)]);
  } else if (i < 65536) {          // BfT [128 n][128 k]: [wl1_rh | wr1_ht]
    int j = i - 49152; int c = j >> 7, k = j & 127;
    a.BfT[j] = f2bf((c < 64) ? a.wl1_rh[k*64 + c] : a.wr1_ht[k*64 + (c - 64)]);
  } else if (i < 163840) {         // B2T [384 n][256 k], n>=349 -> 0
    int j = i - 65536; int c = j >> 8, k = j & 255;
    float v = 0.f;
    if (c < 349) {
      if (k < 64)       v = a.wl2_wr[k * 349 + c];
      else if (k < 128) v = a.wl2_ci[(k - 64) * 349 + c];
      else if (k < 192) v = a.wl2_rh[(k - 128) * 349 + c];
      else { int kk = k - 192; v = a.wr2_wr[kk*349+c] + a.wr2_ci[kk*349+c] + a.wr2_rh[kk*349+c]; }
    }
    a.B2T[j] = f2bf(v);
  } else if (i < 164096) {         // biasP 256
    int c = i - 163840;
    a.biasP[c] = (c < 192) ? 0.f : (a.b1_wr[c-192] + a.b1_ci[c-192] + a.b1_rh[c-192]);
  } else if (i < 164224) {         // biasA 128
    int c = i - 164096;
    a.biasA[c] = (c < 64) ? 0.f : a.b1_rw[c - 64];
  } else if (i < 164352) {         // biasF 128
    int c = i - 164224;
    a.biasF[c] = (c < 64) ? 0.f : a.b1_ht[c - 64];
  } else {                         // bias2 384 (padded with 0)
    int c = i - 164352;
    a.bias2[c] = (c < 349) ? (a.b2_wr[c] + a.b2_ci[c] + a.b2_rh[c]) : 0.f;
  }
}

// fused: blocks [0,NPARTBLK) partition edges; blocks [NPARTBLK, +PREP_BLKS) do weight prep
__global__ __launch_bounds__(256) void part_prep_k(
    const int* __restrict__ wr, const int* __restrict__ rw,
    const int* __restrict__ ci, const int* __restrict__ ht,
    const int* __restrict__ rh, int* __restrict__ bcursor,
    unsigned int* __restrict__ tmp, PrepArgs pa) {
  __shared__ int cnt[NBUCK];
  __shared__ int res[NBUCK];
  int tid = threadIdx.x;
  int blk = blockIdx.x;
  if (blk >= NPARTBLK) {
    prep_body(pa, (blk - NPARTBLK) * 256 + tid);
    return;
  }
  for (int i = tid; i < NBUCK; i += 256) cnt[i] = 0;
  __syncthreads();
  int e0 = blk * EPB;
#pragma unroll 4
  for (int it = 0; it < EPB / 256; ++it) {
    int e = e0 + it * 256 + tid;
    if (e < E_TOT) {
      const int* ei; int el, db, E;
      edec(e, wr, rw, ci, ht, rh, ei, el, db, E);
      int g = db + ei[E + el];
      atomicAdd(&cnt[g >> BSH], 1);
    }
  }
  __syncthreads();
  for (int i = tid; i < NBUCK; i += 256) {
    int c = cnt[i];
    res[i] = c ? atomicAdd(&bcursor[i], c) : 0;
  }
  __syncthreads();
  for (int i = tid; i < NBUCK; i += 256) cnt[i] = 0;
  __syncthreads();
#pragma unroll 4
  for (int it = 0; it < EPB / 256; ++it) {
    int e = e0 + it * 256 + tid;
    if (e < E_TOT) {
      const int* ei; int el, db, E;
      edec(e, wr, rw, ci, ht, rh, ei, el, db, E);
      int g = db + ei[E + el];
      int src = ei[el];
      int b = g >> BSH;
      int p = res[b] + atomicAdd(&cnt[b], 1);
      tmp[p] = ((unsigned int)(g & 1023) << 17) | (unsigned int)src;
    }
  }
}

// one block per 1024-node bucket: per-node degrees in LDS, block scan, compact
// extent via global cursor, emit rbeg/rend, scatter colall.
__global__ __launch_bounds__(256) void build_bucket_k(
    const unsigned int* __restrict__ tmp, const int* __restrict__ bcursor,
    int* __restrict__ gcur, int* __restrict__ rbeg, int* __restrict__ rend,
    int* __restrict__ colall) {
  __shared__ int sdeg[1024];
  __shared__ int ssum[256];
  __shared__ int sbase;
  int tid = threadIdx.x;
  int b = blockIdx.x;
  int beg = b * BCAP, end = bcursor[b];
  for (int i = tid; i < 1024; i += 256) sdeg[i] = 0;
  __syncthreads();
  for (int i = beg + tid; i < end; i += 256) {
    atomicAdd(&sdeg[(int)(tmp[i] >> 17)], 1);
  }
  __syncthreads();
  int i0 = tid * 4;
  int v0 = sdeg[i0], v1 = sdeg[i0 + 1], v2 = sdeg[i0 + 2], v3 = sdeg[i0 + 3];
  int s = v0 + v1 + v2 + v3;
  ssum[tid] = s; __syncthreads();
  int val = s;
  for (int off = 1; off < 256; off <<= 1) {
    int t = (tid >= off) ? ssum[tid - off] : 0;
    __syncthreads();
    val += t; ssum[tid] = val;
    __syncthreads();
  }
  if (tid == 255) sbase = atomicAdd(gcur, val);   // val@255 = bucket total
  __syncthreads();
  int base = sbase + (val - s);
  int e0 = base, e1 = base + v0, e2 = base + v0 + v1, e3 = base + v0 + v1 + v2;
  int n0 = b << BSH;
  if (n0 + i0     < NDEG) { rbeg[n0 + i0]     = e0; rend[n0 + i0]     = e0 + v0; }
  if (n0 + i0 + 1 < NDEG) { rbeg[n0 + i0 + 1] = e1; rend[n0 + i0 + 1] = e1 + v1; }
  if (n0 + i0 + 2 < NDEG) { rbeg[n0 + i0 + 2] = e2; rend[n0 + i0 + 2] = e2 + v2; }
  if (n0 + i0 + 3 < NDEG) { rbeg[n0 + i0 + 3] = e3; rend[n0 + i0 + 3] = e3 + v3; }
  __syncthreads();
  sdeg[i0] = e0; sdeg[i0 + 1] = e1; sdeg[i0 + 2] = e2; sdeg[i0 + 3] = e3;
  __syncthreads();
  for (int i = beg + tid; i < end; i += 256) {
    unsigned int pk = tmp[i];
    int p = atomicAdd(&sdeg[(int)(pk >> 17)], 1);
    colall[p] = (int)(pk & 0x1FFFFu);
  }
}

// ---------------- MFMA GEMM core (bf16, 128x128 tile, BK=32, 4 waves 2x2) ----------------
static __device__ __forceinline__ void stC(float* p, float v) { *p = v; }
static __device__ __forceinline__ void stC(u16* p, float v)   { *p = f2bf(v); }

// f32 -> packed bf16 via v_cvt_pk_bf16_f32 (RTNE, same rounding as f2bf)
static __device__ __forceinline__ void ld8(const float* p, uint4& v) {
  const float4 f0 = *(const float4*)p;
  const float4 f1 = *(const float4*)(p + 4);
  asm("v_cvt_pk_bf16_f32 %0, %1, %2" : "=v"(v.x) : "v"(f0.x), "v"(f0.y));
  asm("v_cvt_pk_bf16_f32 %0, %1, %2" : "=v"(v.y) : "v"(f0.z), "v"(f0.w));
  asm("v_cvt_pk_bf16_f32 %0, %1, %2" : "=v"(v.z) : "v"(f1.x), "v"(f1.y));
  asm("v_cvt_pk_bf16_f32 %0, %1, %2" : "=v"(v.w) : "v"(f1.z), "v"(f1.w));
}

// LDS content: row r, chunk c holds global chunk (c ^ ((r>>1)&3)).
// bf16 A and Bt stage via global_load_lds with pre-swizzled SOURCE chunk + linear dest.
// f32 A stages via regs with cvt_pk f32->bf16.
template <typename AT, typename CT>
static __device__ __forceinline__ void gemm_core(
    const AT* __restrict__ A, const u16* __restrict__ Bt,
    const float* __restrict__ bias, CT* __restrict__ C,
    int M, int N, int K, int row0, int col0, u16* As, u16* Bs) {
  int tid = threadIdx.x;
  int lane = tid & 63;
  int w = tid >> 6;
  int wr = (w >> 1) << 6, wc = (w & 1) << 6;
  int l15 = lane & 15, lh = lane >> 4;
  f32x4 acc[4][4] = {};
  int rchunk = ((lh ^ ((l15 >> 1) & 3)) << 3);
  for (int k0 = 0; k0 < K; k0 += 32) {
    __syncthreads();
#pragma unroll
    for (int it = 0; it < 2; ++it) {             // A: 128 rows x 32 k
      int idx = tid + it * 256;
      int r = idx >> 2, kh = idx & 3;
      int skh = kh ^ ((r >> 1) & 3);
      if constexpr (__is_same(AT, u16)) {
        gl_lds16(A + (size_t)(row0 + r) * K + k0 + skh * 8,
                 As + (size_t)(idx & ~63) * 8);
      } else {
        uint4 v = {0u, 0u, 0u, 0u};
        int row = row0 + r;
        if (row < M) ld8(A + (size_t)row * K + k0 + skh * 8, v);
        *(uint4*)&As[(size_t)idx * 8] = v;
      }
    }
#pragma unroll
    for (int it = 0; it < 2; ++it) {             // B: 128 cols x 32 k (always bf16)
      int idx = tid + it * 256;
      int r = idx >> 2, kh = idx & 3;
      int skh = kh ^ ((r >> 1) & 3);
      gl_lds16(Bt + (size_t)(col0 + r) * K + k0 + skh * 8,
               Bs + (size_t)(idx & ~63) * 8);
    }
    __syncthreads();
    bf16x8 af[4], bfr[4];
#pragma unroll
    for (int m = 0; m < 4; ++m)
      af[m] = *(const bf16x8*)&As[(wr + m * 16 + l15) * 32 + rchunk];
#pragma unroll
    for (int n = 0; n < 4; ++n)
      bfr[n] = *(const bf16x8*)&Bs[(wc + n * 16 + l15) * 32 + rchunk];
#pragma unroll
    for (int m = 0; m < 4; ++m)
#pragma unroll
      for (int n = 0; n < 4; ++n)
        acc[m][n] = __builtin_amdgcn_mfma_f32_16x16x32_bf16(af[m], bfr[n], acc[m][n], 0, 0, 0);
  }
#pragma unroll
  for (int n = 0; n < 4; ++n) {
    int col = col0 + wc + n * 16 + l15;
    if (col >= N) continue;
    float bv = bias[col];
#pragma unroll
    for (int m = 0; m < 4; ++m) {
      int rowb = row0 + wr + m * 16 + (lh << 2);
#pragma unroll
      for (int j = 0; j < 4; ++j) {
        int r = rowb + j;
        if (r < M) stC(C + (size_t)r * N + col, acc[m][n][j] + bv);
      }
    }
  }
}

// fused layer-1 GEMMs: blocks [0,1564)=paper(782x2), [1564,2346)=author(782x1), [2346,2737)=field(391x1)
__global__ __launch_bounds__(256) void gemm_l1_k(
    const float* __restrict__ xp, const float* __restrict__ xa, const float* __restrict__ xf,
    const u16* __restrict__ BpT, const u16* __restrict__ BaT, const u16* __restrict__ BfT,
    const float* __restrict__ biasP, const float* __restrict__ biasA, const float* __restrict__ biasF,
    u16* __restrict__ yp, u16* __restrict__ ya, u16* __restrict__ yf) {
  __shared__ __align__(16) u16 As[128 * 32];
  __shared__ __align__(16) u16 Bs[128 * 32];
  int id = blockIdx.x;
  if (id < 1564) {
    int rx = id % 782, cy = id / 782;
    gemm_core<float, u16>(xp, BpT, biasP, yp, NPAPER, 256, FIN, rx * 128, cy * 128, As, Bs);
  } else if (id < 2346) {
    gemm_core<float, u16>(xa, BaT, biasA, ya, NAUTHOR, 128, FIN, (id - 1564) * 128, 0, As, Bs);
  } else {
    gemm_core<float, u16>(xf, BfT, biasF, yf, NFIELD, 128, FIN, (id - 2346) * 128, 0, As, Bs);
  }
}

// final GEMM: A bf16 (yp), C fp32 (out). Tail rows >= M read <=49KB past yp into ya
// (valid workspace); results discarded by predicated C-write.
__global__ __launch_bounds__(256) void gemm_out_k(
    const u16* __restrict__ A, const u16* __restrict__ Bt,
    const float* __restrict__ bias, float* __restrict__ C) {
  __shared__ __align__(16) u16 As[128 * 32];
  __shared__ __align__(16) u16 Bs[128 * 32];
  gemm_core<u16, float>(A, Bt, bias, C, NPAPER, OUTF, 256,
                        blockIdx.x * 128, blockIdx.y * 128, As, Bs);
}

// ---------------- aggregation: 2 nodes/wave (32 lanes/node), u32 gathers, 8-deep ----------------
// CFG 0: L1 paper (wr+ci+rh means + self + relu -> yp[:,192:256])
// CFG 1: L1 author (rw mean + self + relu -> ya[:,64:128])
// CFG 2: L1 field (ht mean + self + relu -> yf[:,64:128])
// CFG 3: L2 paper (wr/ci/rh means over a1/p1/f1 -> yp[:,0:192])
template <int CFG>
static __device__ __forceinline__ void agg_body(
    int node, int l, const int* __restrict__ rbeg, const int* __restrict__ rend,
    const int* __restrict__ colall,
    u16* __restrict__ ya, u16* __restrict__ yp, u16* __restrict__ yf) {
  constexpr int T = (CFG == 0 || CFG == 3) ? 3 : 1;
  constexpr bool CMB = (CFG != 3);
  constexpr int rpbs[4][3] = {{DB_WR, DB_CI, DB_RH}, {DB_RW, 0, 0}, {DB_HT, 0, 0}, {DB_WR, DB_CI, DB_RH}};
  constexpr int ssel[4][3] = {{0, 1, 2}, {1, 1, 1}, {1, 1, 1}, {0, 1, 2}};
  constexpr int st2s[4][3] = {{64, 128, 64}, {128, 128, 128}, {128, 128, 128}, {64, 128, 64}};
  constexpr int co2s[4][3] = {{0, 0, 0}, {32, 32, 32}, {64, 64, 64}, {32, 96, 32}};
  constexpr int SST2 = (CFG == 0) ? 128 : 64;
  constexpr int SCO2 = (CFG == 0) ? 96 : 32;
  constexpr int OST2 = (CFG == 0 || CFG == 3) ? 128 : 64;
  constexpr int OCO2 = (CFG == 0) ? 96 : ((CFG == 3) ? 0 : 32);

  float totx = 0.f, toty = 0.f;
#pragma unroll
  for (int t = 0; t < T; ++t) {
    const u16* sp = (ssel[CFG][t] == 0) ? ya : ((ssel[CFG][t] == 1) ? yp : yf);
    const u32* s32 = (const u32*)sp + co2s[CFG][t] + l;
    const int st2 = st2s[CFG][t];
    int b = rbeg[rpbs[CFG][t] + node];
    int e = rend[rpbs[CFG][t] + node];
    float ax = 0.f, ay = 0.f;
    for (int i = b; __any(i < e); i += 8) {
      u32 v0 = 0, v1 = 0, v2 = 0, v3 = 0, v4 = 0, v5 = 0, v6 = 0, v7 = 0;
      if (i < e)     v0 = s32[colall[i]     * st2];
      if (i + 1 < e) v1 = s32[colall[i + 1] * st2];
      if (i + 2 < e) v2 = s32[colall[i + 2] * st2];
      if (i + 3 < e) v3 = s32[colall[i + 3] * st2];
      if (i + 4 < e) v4 = s32[colall[i + 4] * st2];
      if (i + 5 < e) v5 = s32[colall[i + 5] * st2];
      if (i + 6 < e) v6 = s32[colall[i + 6] * st2];
      if (i + 7 < e) v7 = s32[colall[i + 7] * st2];
      ax += ((ub2f(v0 << 16) + ub2f(v1 << 16)) + (ub2f(v2 << 16) + ub2f(v3 << 16))) +
            ((ub2f(v4 << 16) + ub2f(v5 << 16)) + (ub2f(v6 << 16) + ub2f(v7 << 16)));
      ay += ((ub2f(v0 & 0xffff0000u) + ub2f(v1 & 0xffff0000u)) +
             (ub2f(v2 & 0xffff0000u) + ub2f(v3 & 0xffff0000u))) +
            ((ub2f(v4 & 0xffff0000u) + ub2f(v5 & 0xffff0000u)) +
             (ub2f(v6 & 0xffff0000u) + ub2f(v7 & 0xffff0000u)));
    }
    float dn = 1.f / fmaxf((float)(e - b), 1.f);
    ax *= dn; ay *= dn;
    if constexpr (CMB) { totx += ax; toty += ay; }
    else {
      u32* o32 = (u32*)yp + (size_t)node * 128 + t * 32 + l;
      *o32 = (u32)f2bf(ax) | ((u32)f2bf(ay) << 16);
    }
  }
  if constexpr (CMB) {
    const u16* sb = (CFG == 0) ? yp : ((CFG == 1) ? ya : yf);
    u32 sv = ((const u32*)sb)[(size_t)node * SST2 + SCO2 + l];
    totx += ub2f(sv << 16);
    toty += ub2f(sv & 0xffff0000u);
    totx = fmaxf(totx, 0.f);
    toty = fmaxf(toty, 0.f);
    u16* ob = (CFG == 0) ? yp : ((CFG == 1) ? ya : yf);
    ((u32*)ob)[(size_t)node * OST2 + OCO2 + l] = (u32)f2bf(totx) | ((u32)f2bf(toty) << 16);
  }
}

// fused L1 aggregation: blocks [0,12500)=paper, [12500,25000)=author, [25000,31250)=field
__global__ __launch_bounds__(256) void agg_l1_k(
    const int* __restrict__ rbeg, const int* __restrict__ rend,
    const int* __restrict__ colall,
    u16* __restrict__ ya, u16* __restrict__ yp, u16* __restrict__ yf) {
  int tid = threadIdx.x;
  int lane = tid & 63;
  int half = lane >> 5, l = lane & 31;
  int blk = blockIdx.x;
  if (blk < 12500) {
    int node = (int)(((blk * 256u + (unsigned)tid) >> 6) * 2 + half);
    agg_body<0>(node, l, rbeg, rend, colall, ya, yp, yf);
  } else if (blk < 25000) {
    int node = (int)((((blk - 12500) * 256u + (unsigned)tid) >> 6) * 2 + half);
    agg_body<1>(node, l, rbeg, rend, colall, ya, yp, yf);
  } else {
    int node = (int)((((blk - 25000) * 256u + (unsigned)tid) >> 6) * 2 + half);
    agg_body<2>(node, l, rbeg, rend, colall, ya, yp, yf);
  }
}

__global__ __launch_bounds__(256) void agg_l2_k(
    const int* __restrict__ rbeg, const int* __restrict__ rend,
    const int* __restrict__ colall,
    u16* __restrict__ ya, u16* __restrict__ yp, u16* __restrict__ yf) {
  int tid = threadIdx.x;
  int lane = tid & 63;
  int half = lane >> 5, l = lane & 31;
  int node = (int)(((blockIdx.x * 256u + (unsigned)tid) >> 6) * 2 + half);
  agg_body<3>(node, l, rbeg, rend, colall, ya, yp, yf);
}

// ---------------- host ----------------
extern "C" void kernel_launch(void* const* d_in, const int* in_sizes, int n_in,
                              void* d_out, int out_size, void* d_ws, size_t ws_size,
                              hipStream_t stream) {
  (void)in_sizes; (void)n_in; (void)out_size; (void)ws_size;
  const float* x_paper  = (const float*)d_in[0];
  const float* x_author = (const float*)d_in[1];
  const float* x_field  = (const float*)d_in[2];
  const int* ei_wr = (const int*)d_in[3];
  const int* ei_rw = (const int*)d_in[4];
  const int* ei_ci = (const int*)d_in[5];
  const int* ei_ht = (const int*)d_in[6];
  const int* ei_rh = (const int*)d_in[7];
  float* out = (float*)d_out;

  char* w = (char*)d_ws;
  auto alloc = [&](size_t b) { char* p = w; w += (b + 255) & ~(size_t)255; return p; };
  int* rbeg     = (int*)alloc((size_t)NDEG * 4);
  int* rend     = (int*)alloc((size_t)NDEG * 4);
  int* colall   = (int*)alloc((size_t)E_TOT * 4);
  int* bcursor  = (int*)alloc(512 * 4);
  int* gcur     = (int*)alloc(256);
  // yp cols: [0:64]=ci-proj [64:128]=rw-proj [128:192]=ht-proj [192:256]=self -> p1; later cols 0:192 = L2 means
  u16* yp = (u16*)alloc((size_t)NPAPER * 256 * 2);
  // ya cols: [0:64]=wr-proj, [64:128]=self -> a1
  u16* ya = (u16*)alloc((size_t)NAUTHOR * 128 * 2);
  // yf cols: [0:64]=rh-proj, [64:128]=self -> f1
  u16* yf = (u16*)alloc((size_t)NFIELD * 128 * 2);
  u16* BpT   = (u16*)alloc(32768 * 2);
  u16* BaT   = (u16*)alloc(16384 * 2);
  u16* BfT   = (u16*)alloc(16384 * 2);
  u16* B2T   = (u16*)alloc(98304 * 2);
  float* biasP = (float*)alloc(256 * 4);
  float* biasA = (float*)alloc(128 * 4);
  float* biasF = (float*)alloc(128 * 4);
  float* bias2 = (float*)alloc(384 * 4);

  // tmp (440*22528*4 = 39.6 MB) aliases yp (51.2 MB): build finishes before GEMM writes yp
  unsigned int* tmp = (unsigned int*)yp;

  PrepArgs pa;
  pa.wl1_wr = (const float*)d_in[8];  pa.wr1_wr = (const float*)d_in[9];  pa.b1_wr = (const float*)d_in[10];
  pa.wl1_rw = (const float*)d_in[11]; pa.wr1_rw = (const float*)d_in[12]; pa.b1_rw = (const float*)d_in[13];
  pa.wl1_ci = (const float*)d_in[14]; pa.wr1_ci = (const float*)d_in[15]; pa.b1_ci = (const float*)d_in[16];
  pa.wl1_ht = (const float*)d_in[17]; pa.wr1_ht = (const float*)d_in[18]; pa.b1_ht = (const float*)d_in[19];
  pa.wl1_rh = (const float*)d_in[20]; pa.wr1_rh = (const float*)d_in[21]; pa.b1_rh = (const float*)d_in[22];
  pa.wl2_wr = (const float*)d_in[23]; pa.wr2_wr = (const float*)d_in[24]; pa.b2_wr = (const float*)d_in[25];
  pa.wl2_ci = (const float*)d_in[26]; pa.wr2_ci = (const float*)d_in[27]; pa.b2_ci = (const float*)d_in[28];
  pa.wl2_rh = (const float*)d_in[29]; pa.wr2_rh = (const float*)d_in[30]; pa.b2_rh = (const float*)d_in[31];
  pa.BpT = BpT; pa.BaT = BaT; pa.BfT = BfT; pa.B2T = B2T;
  pa.biasP = biasP; pa.biasA = biasA; pa.biasF = biasF; pa.bias2 = bias2;

  initcur_k<<<2, 256, 0, stream>>>(bcursor, gcur);
  part_prep_k<<<NPARTBLK + PREP_BLKS, 256, 0, stream>>>(
      ei_wr, ei_rw, ei_ci, ei_ht, ei_rh, bcursor, tmp, pa);
  build_bucket_k<<<NBUCK, 256, 0, stream>>>(tmp, bcursor, gcur, rbeg, rend, colall);

  // layer-1 projections (fused paper+author+field) — MFMA bf16
  gemm_l1_k<<<2737, 256, 0, stream>>>(x_paper, x_author, x_field,
      BpT, BaT, BfT, biasP, biasA, biasF, yp, ya, yf);

  // layer-1 aggregation (fused): p1 -> yp[:,192:256], a1 -> ya[:,64:128], f1 -> yf[:,64:128]
  agg_l1_k<<<31250, 256, 0, stream>>>(rbeg, rend, colall, ya, yp, yf);
  // layer-2 aggregation: means into yp[:,0:192] (reads a1, p1, f1)
  agg_l2_k<<<12500, 256, 0, stream>>>(rbeg, rend, colall, ya, yp, yf);

  // final fused GEMM: [m_wr | m_ci | m_rh | p1] @ B2T + bias2 -> out  (N=349 padded to 384)
  gemm_out_k<<<dim3(782, 3), 256, 0, stream>>>(yp, B2T, bias2, out);
}